// Round 7
// baseline (283.929 us; speedup 1.0000x reference)
//
#include <hip/hip_runtime.h>
#include <hip/hip_bf16.h>

#define HID 1024
#define NH 16
#define HEAD 64
#define WIN 256
#define SEQ 4096
#define BATCH 4
#define NROWS (BATCH * SEQ)   // 16384
#define LN_EPS 1e-5f

typedef unsigned short u16;
typedef __bf16 bf16x8 __attribute__((ext_vector_type(8)));
typedef float f32x4 __attribute__((ext_vector_type(4)));

static __device__ inline float bfu(u16 u) {
    union { unsigned int i; float f; } x;
    x.i = ((unsigned int)u) << 16;
    return x.f;
}

static __device__ inline u16 f2bf(float f) {
    union { float f; unsigned int i; } x;
    x.f = f;
    unsigned int lsb = (x.i >> 16) & 1u;
    x.i += 0x7fffu + lsb;   // round-to-nearest-even
    return (u16)(x.i >> 16);
}

// ---------------------------------------------------------------- fused LN1 + weight convert
__global__ __launch_bounds__(256) void ln1_conv(
    const float* __restrict__ x, const float* __restrict__ g,
    const float* __restrict__ b, u16* __restrict__ out,
    const float* __restrict__ wq, const float* __restrict__ wk,
    const float* __restrict__ wv, const float* __restrict__ wp,
    u16* __restrict__ wo)
{
    __shared__ float red[8];
    int t = threadIdx.x;
    if (blockIdx.x >= NROWS) {
        int i = (blockIdx.x - NROWS) * 256 + t;
        const int n = 1024 * 1024;
        wo[i]         = f2bf(wq[i]);
        wo[n + i]     = f2bf(wk[i]);
        wo[2 * n + i] = f2bf(wv[i]);
        wo[3 * n + i] = f2bf(wp[i]);
        return;
    }
    int row = blockIdx.x;
    float4 v = ((const float4*)(x + (size_t)row * HID))[t];
    float s  = v.x + v.y + v.z + v.w;
    float ss = v.x * v.x + v.y * v.y + v.z * v.z + v.w * v.w;
    #pragma unroll
    for (int off = 32; off; off >>= 1) { s += __shfl_down(s, off); ss += __shfl_down(ss, off); }
    int wave = t >> 6, lane = t & 63;
    if (lane == 0) { red[wave] = s; red[4 + wave] = ss; }
    __syncthreads();
    float S  = red[0] + red[1] + red[2] + red[3];
    float SS = red[4] + red[5] + red[6] + red[7];
    float mean = S * (1.f / HID);
    float var  = SS * (1.f / HID) - mean * mean;
    float inv  = rsqrtf(var + LN_EPS);
    float4 gv = ((const float4*)g)[t];
    float4 bv = ((const float4*)b)[t];
    ushort4 o;
    o.x = f2bf((v.x - mean) * inv * gv.x + bv.x);
    o.y = f2bf((v.y - mean) * inv * gv.y + bv.y);
    o.z = f2bf((v.z - mean) * inv * gv.z + bv.z);
    o.w = f2bf((v.w - mean) * inv * gv.w + bv.w);
    ((ushort4*)(out + (size_t)row * HID))[t] = o;
}

// ---------------------------------------------------------------- 256x256 bf16 GEMM, persistent grid
// 8 waves (2M x 4N), BK=64. TWO barriers per K-tile: [stage 8 GLDS; vmcnt(8);
// barrier] ... [24 ds_read + 64 MFMA, compiler-scheduled lgkm] ... [barrier].
// Counted vmcnt gives each stage a full K-tile of lead; T2 swizzle; T5 setprio.
#define GLDS(gp, lp) __builtin_amdgcn_global_load_lds( \
    (const __attribute__((address_space(1))) void*)(gp), \
    (__attribute__((address_space(3))) void*)(lp), 16, 0, 0)

__global__ __launch_bounds__(512, 2) void gemm256(
    const u16* __restrict__ A, const u16* __restrict__ W,
    u16* __restrict__ C, int K, int ldc, int ntiles)
{
    __shared__ __align__(16) u16 sA[2][256 * 64];   // 64 KB
    __shared__ __align__(16) u16 sB[2][256 * 64];   // 64 KB

    const int tid = threadIdx.x;
    const int wave = tid >> 6, lane = tid & 63;
    const int wr = wave >> 2, wc = wave & 3;

    // staging geometry (pre-swizzled source column, linear LDS dest)
    const int rp = tid >> 3;                                    // 0..63 row in 8KB unit
    const int rowA = (rp < 32 ? rp : rp + 96);
    const int colE = (((tid & 7) * 16) ^ ((rp & 7) << 4)) >> 1; // elem col 0..63
    // swizzled k-byte for kh=0 (kh=1 -> ^64)
    const int c0 = ((lane >> 4) * 16) ^ ((lane & 7) << 4);
    const int li = lane & 15;

    const int nk = K >> 6;

    // first assignment + prologue stage
    int a = blockIdx.x;
    int wgl = a >> 3;
    int bm = (a & 7) * 8 + (wgl & 7);
    int bn = wgl >> 3;
    const u16* gA = A + (size_t)(bm * 256 + rowA) * K + colE;
    const u16* gB = W + (size_t)(bn * 256 + rp) * K + colE;
    #pragma unroll
    for (int w = 0; w < 4; ++w) GLDS(gB + (size_t)w * 64 * K, &sB[0][w * 4096 + tid * 8]);
    #pragma unroll
    for (int p = 0; p < 4; ++p) GLDS(gA + (size_t)p * 32 * K, &sA[0][p * 4096 + tid * 8]);

    while (true) {
        f32x4 acc[8][4];
        #pragma unroll
        for (int m = 0; m < 8; ++m)
            #pragma unroll
            for (int n = 0; n < 4; ++n) {
                f32x4 z = {0.f, 0.f, 0.f, 0.f};
                acc[m][n] = z;
            }

        for (int kt = 0; kt < nk; ++kt) {
            const int b = kt & 1;
            const u16* rA = sA[b];
            const u16* rB = sB[b];
            u16* dA = sA[b ^ 1];
            u16* dB = sB[b ^ 1];
            const bool pf = (kt + 1 < nk);

            if (pf) {
                const size_t ko = (size_t)(kt + 1) * 64;
                #pragma unroll
                for (int w = 0; w < 4; ++w)
                    GLDS(gB + (size_t)w * 64 * K + ko, &dB[w * 4096 + tid * 8]);
                #pragma unroll
                for (int p = 0; p < 4; ++p)
                    GLDS(gA + (size_t)p * 32 * K + ko, &dA[p * 4096 + tid * 8]);
                asm volatile("s_waitcnt vmcnt(8)" ::: "memory");
            } else {
                asm volatile("s_waitcnt vmcnt(0)" ::: "memory");
            }
            __builtin_amdgcn_sched_barrier(0);
            __builtin_amdgcn_s_barrier();
            __builtin_amdgcn_sched_barrier(0);

            bf16x8 bF0[4], bF1[4], aF0[8], aF1[8];
            #pragma unroll
            for (int n = 0; n < 4; ++n)
                bF0[n] = *(const bf16x8*)&rB[wc * 4096 + (n * 16 + li) * 64 + (c0 >> 1)];
            #pragma unroll
            for (int mf = 0; mf < 8; ++mf)
                aF0[mf] = *(const bf16x8*)&rA[(mf >> 1) * 4096 +
                    (wr * 32 + (mf & 1) * 16 + li) * 64 + (c0 >> 1)];
            __builtin_amdgcn_s_setprio(1);
            #pragma unroll
            for (int mf = 0; mf < 8; ++mf)
                #pragma unroll
                for (int n = 0; n < 4; ++n)
                    acc[mf][n] = __builtin_amdgcn_mfma_f32_16x16x32_bf16(
                        aF0[mf], bF0[n], acc[mf][n], 0, 0, 0);
            #pragma unroll
            for (int n = 0; n < 4; ++n)
                bF1[n] = *(const bf16x8*)&rB[wc * 4096 + (n * 16 + li) * 64 + ((c0 ^ 64) >> 1)];
            #pragma unroll
            for (int mf = 0; mf < 8; ++mf)
                aF1[mf] = *(const bf16x8*)&rA[(mf >> 1) * 4096 +
                    (wr * 32 + (mf & 1) * 16 + li) * 64 + ((c0 ^ 64) >> 1)];
            #pragma unroll
            for (int mf = 0; mf < 8; ++mf)
                #pragma unroll
                for (int n = 0; n < 4; ++n)
                    acc[mf][n] = __builtin_amdgcn_mfma_f32_16x16x32_bf16(
                        aF1[mf], bF1[n], acc[mf][n], 0, 0, 0);
            __builtin_amdgcn_s_setprio(0);
            __builtin_amdgcn_sched_barrier(0);
            __builtin_amdgcn_s_barrier();
            __builtin_amdgcn_sched_barrier(0);
        }

        const int bmC = bm, bnC = bn;
        a += gridDim.x;
        const bool more = (a < ntiles);
        if (more) {
            wgl = a >> 3; bm = (a & 7) * 8 + (wgl & 7); bn = wgl >> 3;
            gA = A + (size_t)(bm * 256 + rowA) * K + colE;
            gB = W + (size_t)(bn * 256 + rp) * K + colE;
            #pragma unroll
            for (int w = 0; w < 4; ++w) GLDS(gB + (size_t)w * 64 * K, &sB[0][w * 4096 + tid * 8]);
            #pragma unroll
            for (int p = 0; p < 4; ++p) GLDS(gA + (size_t)p * 32 * K, &sA[0][p * 4096 + tid * 8]);
        }

        #pragma unroll
        for (int mf = 0; mf < 8; ++mf) {
            int row0 = bmC * 256 + wr * 128 + mf * 16 + ((lane >> 4) << 2);
            #pragma unroll
            for (int n = 0; n < 4; ++n) {
                int col = bnC * 256 + wc * 64 + n * 16 + li;
                #pragma unroll
                for (int r = 0; r < 4; ++r)
                    C[(size_t)(row0 + r) * ldc + col] = f2bf(acc[mf][n][r]);
            }
        }
        if (!more) break;
    }
}

// ---------------------------------------------------------------- logits: aw[b][h][s] = exp(dot/8 + mask_add)
__global__ __launch_bounds__(256) void logits_kernel(
    const u16* __restrict__ x, int xstride,
    const float* __restrict__ vec, const float* __restrict__ mask,
    float* __restrict__ aw)
{
    int h = blockIdx.y, b = blockIdx.z;
    int s = blockIdx.x * 256 + threadIdx.x;
    __shared__ float vl[HEAD];
    if (threadIdx.x < HEAD) vl[threadIdx.x] = vec[h * HEAD + threadIdx.x];
    __syncthreads();
    const uint4* xr = (const uint4*)(x + ((size_t)(b * SEQ + s)) * xstride + h * HEAD);
    float dot = 0.f;
    #pragma unroll
    for (int i = 0; i < 8; ++i) {
        uint4 v = xr[i];
        const u16* p = (const u16*)&v;
        #pragma unroll
        for (int j = 0; j < 8; ++j) dot += bfu(p[j]) * vl[i * 8 + j];
    }
    float ma = (1.0f - mask[b * SEQ + s]) * -10000.0f;
    aw[((size_t)b * NH + h) * SEQ + s] = expf(dot * 0.125f + ma);
}

// ---------------------------------------------------------------- windowed scan attention, 2 heads/block
// fused==0: out_bf <- windowed avg (bf16). fused==1: outF <- res + win*v (write-only).
__global__ __launch_bounds__(512) void attn_win2(
    const u16* __restrict__ x, int xstride,
    const float* __restrict__ aw_g,
    u16* __restrict__ out_bf,
    const u16* __restrict__ resv,   // qkv base: res in cols 0..1023, v in cols 2048..3071
    float* __restrict__ outF,
    int fused)
{
    int c = blockIdx.x, h2 = blockIdx.y, b = blockIdx.z;
    __shared__ float awl[2][2][WIN];     // [head][chunk][j]
    __shared__ float2 sts[2][8][64];     // [chunk][wave][lane]
    __shared__ float stz[2][8][2];       // [chunk][wave][head]

    int t = threadIdx.x, wave = t >> 6, lane = t & 63;
    int hh = lane >> 5;
    int coff = hh * 64 + (lane & 31) * 2;
    bool havePrev = (c > 0);

    const float* aw0 = aw_g + ((size_t)b * NH + h2 * 2) * SEQ;
    for (int i = t; i < 1024; i += 512) {
        int hd = i >> 9, cc = (i >> 8) & 1, j = i & 255;
        float v = 0.f;
        if (cc == 1) v = aw0[hd * SEQ + c * WIN + j];
        else if (havePrev) v = aw0[hd * SEQ + (c - 1) * WIN + j];
        awl[hd][cc][j] = v;
    }
    __syncthreads();

    const u16* xb = x + (size_t)b * SEQ * xstride + h2 * 128 + coff;
    int jp0 = (havePrev ? c - 1 : c) * WIN;   // clamped when c==0 (aw=0 kills it)
    int jc0 = c * WIN;
    int j0 = wave * 32;

    // step A: per-wave sub-strip totals over rows [j0, j0+32) of both chunks
    float s0a = 0, s0b = 0, s1a = 0, s1b = 0, z0 = 0, z1 = 0;
    #pragma unroll 8
    for (int jj = 0; jj < 32; ++jj) {
        int j = j0 + jj;
        float ap = awl[hh][0][j], ac = awl[hh][1][j];
        unsigned up = *(const unsigned*)(xb + (size_t)(jp0 + j) * xstride);
        unsigned uc = *(const unsigned*)(xb + (size_t)(jc0 + j) * xstride);
        s0a += ap * bfu(up & 0xffff); s0b += ap * bfu(up >> 16); z0 += ap;
        s1a += ac * bfu(uc & 0xffff); s1b += ac * bfu(uc >> 16); z1 += ac;
    }
    sts[0][wave][lane] = make_float2(s0a, s0b);
    sts[1][wave][lane] = make_float2(s1a, s1b);
    if ((lane & 31) == 0) { stz[0][wave][hh] = z0; stz[1][wave][hh] = z1; }
    __syncthreads();

    // step B: carries + chunk-(c-1) totals
    float cs0a = 0, cs0b = 0, cs1a = 0, cs1b = 0, cz0 = 0, cz1 = 0;
    float totsa = 0, totsb = 0, totz = 0;
    #pragma unroll
    for (int w2 = 0; w2 < 8; ++w2) {
        float2 sp = sts[0][w2][lane];
        float zp = stz[0][w2][hh];
        totsa += sp.x; totsb += sp.y; totz += zp;
        if (w2 < wave) {
            cs0a += sp.x; cs0b += sp.y; cz0 += zp;
            float2 sc = sts[1][w2][lane];
            cs1a += sc.x; cs1b += sc.y; cz1 += stz[1][w2][hh];
        }
    }

    // step C: rescan with carries, emit
    float rpa = cs0a, rpb = cs0b, rca = cs1a, rcb = cs1b, rzp = cz0, rzc = cz1;
    size_t rowbase = (size_t)b * SEQ + jc0;
    #pragma unroll 4
    for (int jj = 0; jj < 32; ++jj) {
        int j = j0 + jj;
        float ap = awl[hh][0][j], ac = awl[hh][1][j];
        unsigned up = *(const unsigned*)(xb + (size_t)(jp0 + j) * xstride);
        unsigned uc = *(const unsigned*)(xb + (size_t)(jc0 + j) * xstride);
        rpa += ap * bfu(up & 0xffff); rpb += ap * bfu(up >> 16); rzp += ap;
        rca += ac * bfu(uc & 0xffff); rcb += ac * bfu(uc >> 16); rzc += ac;
        float inv = 1.f / (rzc + totz - rzp);
        float wva = (rca + totsa - rpa) * inv;
        float wvb = (rcb + totsb - rpb) * inv;
        if (fused) {
            size_t roff = (rowbase + j) * 3072 + h2 * 128 + coff;
            unsigned rr = *(const unsigned*)(resv + roff);
            unsigned vv = *(const unsigned*)(resv + roff + 2048);
            float2 o;
            o.x = bfu(rr & 0xffff) + wva * bfu(vv & 0xffff);
            o.y = bfu(rr >> 16)    + wvb * bfu(vv >> 16);
            *(float2*)(outF + (rowbase + j) * HID + h2 * 128 + coff) = o;
        } else {
            unsigned pk = (unsigned)f2bf(wva) | ((unsigned)f2bf(wvb) << 16);
            *(unsigned*)(out_bf + (rowbase + j) * HID + h2 * 128 + coff) = pk;
        }
    }
}

// ---------------------------------------------------------------- residual + LN2 + fused key-attn logits
__global__ __launch_bounds__(256) void resid_ln2(
    const u16* h, u16* qkv,
    const float* __restrict__ g, const float* __restrict__ b,
    const float* __restrict__ ka, const float* __restrict__ mask,
    u16* mixed, float* __restrict__ aw2)
{
    int row = blockIdx.x;
    int t = threadIdx.x;
    ushort4 h4 = ((const ushort4*)(h + (size_t)row * HID))[t];
    ushort4 p4 = ((const ushort4*)(qkv + (size_t)row * 3072))[t];
    ushort4 k4 = ((const ushort4*)(qkv + (size_t)row * 3072 + 1024))[t];
    float r0 = bfu(h4.x) + bfu(p4.x) * bfu(k4.x);
    float r1 = bfu(h4.y) + bfu(p4.y) * bfu(k4.y);
    float r2 = bfu(h4.z) + bfu(p4.z) * bfu(k4.z);
    float r3 = bfu(h4.w) + bfu(p4.w) * bfu(k4.w);
    ushort4 rb;
    rb.x = f2bf(r0); rb.y = f2bf(r1); rb.z = f2bf(r2); rb.w = f2bf(r3);
    ((ushort4*)(qkv + (size_t)row * 3072))[t] = rb;   // residual bf16 over dead pq

    float s  = r0 + r1 + r2 + r3;
    float ss = r0 * r0 + r1 * r1 + r2 * r2 + r3 * r3;
    __shared__ float red[8];
    #pragma unroll
    for (int off = 32; off; off >>= 1) { s += __shfl_down(s, off); ss += __shfl_down(ss, off); }
    int wave = t >> 6, lane = t & 63;
    if (lane == 0) { red[wave] = s; red[4 + wave] = ss; }
    __syncthreads();
    float S  = red[0] + red[1] + red[2] + red[3];
    float SS = red[4] + red[5] + red[6] + red[7];
    float mean = S * (1.f / HID);
    float var  = SS * (1.f / HID) - mean * mean;
    float inv  = rsqrtf(var + LN_EPS);
    float4 gv = ((const float4*)g)[t];
    float4 bv = ((const float4*)b)[t];
    float n0 = (r0 - mean) * inv * gv.x + bv.x;
    float n1 = (r1 - mean) * inv * gv.y + bv.y;
    float n2 = (r2 - mean) * inv * gv.z + bv.z;
    float n3 = (r3 - mean) * inv * gv.w + bv.w;
    ushort4 o;
    o.x = f2bf(n0); o.y = f2bf(n1); o.z = f2bf(n2); o.w = f2bf(n3);
    ((ushort4*)(mixed + (size_t)row * HID))[t] = o;

    // fused logits for second attention: head = t>>4
    float4 kv = ((const float4*)ka)[t];
    float partial = n0 * kv.x + n1 * kv.y + n2 * kv.z + n3 * kv.w;
    partial += __shfl_xor(partial, 1);
    partial += __shfl_xor(partial, 2);
    partial += __shfl_xor(partial, 4);
    partial += __shfl_xor(partial, 8);
    if ((t & 15) == 0) {
        int hh = t >> 4;
        int bb = row >> 12, sl = row & (SEQ - 1);
        float ma = (1.0f - mask[row]) * -10000.0f;
        aw2[((size_t)bb * NH + hh) * SEQ + sl] = expf(partial * 0.125f + ma);
    }
}

extern "C" void kernel_launch(void* const* d_in, const int* in_sizes, int n_in,
                              void* d_out, int out_size, void* d_ws, size_t ws_size,
                              hipStream_t stream)
{
    const float* hidden = (const float*)d_in[0];
    const float* mask   = (const float*)d_in[1];
    const float* Wq     = (const float*)d_in[2];
    const float* Wk     = (const float*)d_in[3];
    const float* Wv     = (const float*)d_in[4];
    const float* Wp     = (const float*)d_in[5];
    const float* qa     = (const float*)d_in[6];
    const float* ka     = (const float*)d_in[7];
    const float* g1     = (const float*)d_in[8];
    const float* b1     = (const float*)d_in[9];
    const float* g2     = (const float*)d_in[10];
    const float* b2     = (const float*)d_in[11];
    float* out = (float*)d_out;

    // workspace: 8 + 32 + 96 + 32 + 1 + 1 = 170 MB
    char* ws = (char*)d_ws;
    u16* wbf = (u16*)ws;       ws += (size_t)4 * 1024 * 1024 * 2;     //  8 MB  Wq|Wk|Wv|Wp bf16
    u16* hbf = (u16*)ws;       ws += (size_t)NROWS * HID * 2;         // 32 MB  h (later: mixed, in place)
    u16* qkv = (u16*)ws;       ws += (size_t)NROWS * 3072 * 2;        // 96 MB  q|k|v (q-cols: pq, then residual)
    u16* pooled = (u16*)ws;    ws += (size_t)NROWS * HID * 2;         // 32 MB  pooled_q
    float* aw1 = (float*)ws;   ws += (size_t)BATCH * NH * SEQ * 4;    //  1 MB
    float* aw2 = (float*)ws;                                          //  1 MB

    ln1_conv<<<NROWS + 4096, 256, 0, stream>>>(hidden, g1, b1, hbf, Wq, Wk, Wv, Wp, wbf);
    // qkv GEMM: 64 bm x 12 bn = 768 tiles, persistent 256 blocks
    gemm256<<<256, 512, 0, stream>>>(hbf, wbf, qkv, HID, 3072, 768);
    logits_kernel<<<dim3(SEQ / 256, NH, BATCH), 256, 0, stream>>>(qkv, 3072, qa, mask, aw1);
    attn_win2<<<dim3(SEQ / WIN, NH / 2, BATCH), 512, 0, stream>>>(
        qkv, 3072, aw1, pooled, (const u16*)nullptr, (float*)nullptr, 0);
    // pooled_q @ Wp.T -> qkv cols 0..1023 (q is dead): 64 bm x 4 bn = 256 tiles
    gemm256<<<256, 512, 0, stream>>>(pooled, wbf + (size_t)3 * 1024 * 1024, qkv, HID, 3072, 256);
    resid_ln2<<<NROWS, 256, 0, stream>>>(hbf, qkv, g2, b2, ka, mask, hbf, aw2);
    // second attention fused with final: out = res + win * v
    attn_win2<<<dim3(SEQ / WIN, NH / 2, BATCH), 512, 0, stream>>>(
        hbf, HID, aw2, (u16*)nullptr, qkv, out, 1);
}

// Round 9
// 273.188 us; speedup vs baseline: 1.0393x; 1.0393x over previous
//
#include <hip/hip_runtime.h>
#include <hip/hip_bf16.h>

#define HID 1024
#define NH 16
#define HEAD 64
#define WIN 256
#define SEQ 4096
#define BATCH 4
#define NROWS (BATCH * SEQ)   // 16384
#define LN_EPS 1e-5f

typedef unsigned short u16;
typedef __bf16 bf16x8 __attribute__((ext_vector_type(8)));
typedef float f32x4 __attribute__((ext_vector_type(4)));

static __device__ inline float bfu(u16 u) {
    union { unsigned int i; float f; } x;
    x.i = ((unsigned int)u) << 16;
    return x.f;
}

static __device__ inline u16 f2bf(float f) {
    union { float f; unsigned int i; } x;
    x.f = f;
    unsigned int lsb = (x.i >> 16) & 1u;
    x.i += 0x7fffu + lsb;   // round-to-nearest-even
    return (u16)(x.i >> 16);
}

// ---------------------------------------------------------------- fused LN1 + weight convert
__global__ __launch_bounds__(256) void ln1_conv(
    const float* __restrict__ x, const float* __restrict__ g,
    const float* __restrict__ b, u16* __restrict__ out,
    const float* __restrict__ wq, const float* __restrict__ wk,
    const float* __restrict__ wv, const float* __restrict__ wp,
    u16* __restrict__ wo)
{
    __shared__ float red[8];
    int t = threadIdx.x;
    if (blockIdx.x >= NROWS) {
        int i = (blockIdx.x - NROWS) * 256 + t;
        const int n = 1024 * 1024;
        wo[i]         = f2bf(wq[i]);
        wo[n + i]     = f2bf(wk[i]);
        wo[2 * n + i] = f2bf(wv[i]);
        wo[3 * n + i] = f2bf(wp[i]);
        return;
    }
    int row = blockIdx.x;
    float4 v = ((const float4*)(x + (size_t)row * HID))[t];
    float s  = v.x + v.y + v.z + v.w;
    float ss = v.x * v.x + v.y * v.y + v.z * v.z + v.w * v.w;
    #pragma unroll
    for (int off = 32; off; off >>= 1) { s += __shfl_down(s, off); ss += __shfl_down(ss, off); }
    int wave = t >> 6, lane = t & 63;
    if (lane == 0) { red[wave] = s; red[4 + wave] = ss; }
    __syncthreads();
    float S  = red[0] + red[1] + red[2] + red[3];
    float SS = red[4] + red[5] + red[6] + red[7];
    float mean = S * (1.f / HID);
    float var  = SS * (1.f / HID) - mean * mean;
    float inv  = rsqrtf(var + LN_EPS);
    float4 gv = ((const float4*)g)[t];
    float4 bv = ((const float4*)b)[t];
    ushort4 o;
    o.x = f2bf((v.x - mean) * inv * gv.x + bv.x);
    o.y = f2bf((v.y - mean) * inv * gv.y + bv.y);
    o.z = f2bf((v.z - mean) * inv * gv.z + bv.z);
    o.w = f2bf((v.w - mean) * inv * gv.w + bv.w);
    ((ushort4*)(out + (size_t)row * HID))[t] = o;
}

// ---------------------------------------------------------------- 256x256 bf16 GEMM, persistent grid
// Round-6 4-phase schedule (verified deterministic): per phase {ds_read subtile,
// 2 GLDS, wait, barrier, setprio, 16 MFMA, setprio, barrier}. TWO counted
// vmcnt(2) per K-tile (ph0 + ph3) — ph3's wait is LOAD-BEARING: the next ph0's
// ds_reads are issued before ph0's own wait, so B0-3/A0/A1 of t+1 must have
// landed by end of t (round-8 lesson: removing it races). Assignment boundary
// gets the same treatment: while-top vmcnt(2)+barrier drains the new prologue.
#define GLDS(gp, lp) __builtin_amdgcn_global_load_lds( \
    (const __attribute__((address_space(1))) void*)(gp), \
    (__attribute__((address_space(3))) void*)(lp), 16, 0, 0)

#define PHASE(MH, KH, LOADB, STAGE_CODE, WAIT_CODE)                            \
  {                                                                            \
    if (LOADB) {                                                               \
      _Pragma("unroll") for (int n = 0; n < 4; ++n)                            \
        bF[n] = *(const bf16x8*)&rB[wc * 4096 +                                \
            (n * 16 + li) * 64 + ((c0 ^ ((KH) << 6)) >> 1)];                   \
    }                                                                          \
    bf16x8 aF[4];                                                              \
    _Pragma("unroll") for (int i = 0; i < 4; ++i) {                            \
      const int mf = (MH) * 4 + i;                                             \
      aF[i] = *(const bf16x8*)&rA[(mf >> 1) * 4096 +                           \
          (wr * 32 + (mf & 1) * 16 + li) * 64 +                                \
          ((c0 ^ ((KH) << 6)) >> 1)];                                          \
    }                                                                          \
    STAGE_CODE                                                                 \
    WAIT_CODE                                                                  \
    __builtin_amdgcn_s_barrier();                                              \
    __builtin_amdgcn_sched_barrier(0);                                         \
    __builtin_amdgcn_s_setprio(1);                                             \
    _Pragma("unroll") for (int i = 0; i < 4; ++i)                              \
      _Pragma("unroll") for (int n = 0; n < 4; ++n)                            \
        acc[(MH) * 4 + i][n] = __builtin_amdgcn_mfma_f32_16x16x32_bf16(        \
            aF[i], bF[n], acc[(MH) * 4 + i][n], 0, 0, 0);                      \
    __builtin_amdgcn_s_setprio(0);                                             \
    __builtin_amdgcn_s_barrier();                                              \
    __builtin_amdgcn_sched_barrier(0);                                         \
  }

__global__ __launch_bounds__(512, 2) void gemm256(
    const u16* __restrict__ A, const u16* __restrict__ W,
    u16* __restrict__ C, int K, int ldc, int ntiles,
    const float* __restrict__ qa,     // if non-null: fused logits for bn<4 tiles
    const float* __restrict__ mask,
    float* __restrict__ awout)
{
    __shared__ __align__(16) u16 sA[2][256 * 64];   // 64 KB
    __shared__ __align__(16) u16 sB[2][256 * 64];   // 64 KB

    const int tid = threadIdx.x;
    const int wave = tid >> 6, lane = tid & 63;
    const int wr = wave >> 2, wc = wave & 3;

    // staging geometry (pre-swizzled source column, linear LDS dest)
    const int rp = tid >> 3;                                    // 0..63 row in 8KB unit
    const int rowA = (rp < 32 ? rp : rp + 96);
    const int colE = (((tid & 7) * 16) ^ ((rp & 7) << 4)) >> 1; // elem col 0..63
    // swizzled k-byte for kh=0 (kh=1 -> ^64)
    const int c0 = ((lane >> 4) * 16) ^ ((lane & 7) << 4);
    const int li = lane & 15;

    const int nk = K >> 6;

    // first assignment + prologue stage
    int a = blockIdx.x;
    int wgl = a >> 3;
    int bm = (a & 7) * 8 + (wgl & 7);
    int bn = wgl >> 3;
    const u16* gA = A + (size_t)(bm * 256 + rowA) * K + colE;
    const u16* gB = W + (size_t)(bn * 256 + rp) * K + colE;
    #pragma unroll
    for (int w = 0; w < 4; ++w) GLDS(gB + (size_t)w * 64 * K, &sB[0][w * 4096 + tid * 8]);
    #pragma unroll
    for (int p = 0; p < 4; ++p) GLDS(gA + (size_t)p * 32 * K, &sA[0][p * 4096 + tid * 8]);

    while (true) {
        // assignment-boundary drain: B0-3, A0, A1 of this assignment's tile 0
        // must land before kt=0 ph0's ds_reads (A2,A3 drained by ph0's wait).
        asm volatile("s_waitcnt vmcnt(2)" ::: "memory");
        __builtin_amdgcn_sched_barrier(0);
        __builtin_amdgcn_s_barrier();
        __builtin_amdgcn_sched_barrier(0);

        f32x4 acc[8][4];
        #pragma unroll
        for (int m = 0; m < 8; ++m)
            #pragma unroll
            for (int n = 0; n < 4; ++n) {
                f32x4 z = {0.f, 0.f, 0.f, 0.f};
                acc[m][n] = z;
            }

        for (int kt = 0; kt < nk; ++kt) {
            const int b = kt & 1;
            const u16* rA = sA[b];
            const u16* rB = sB[b];
            u16* dA = sA[b ^ 1];
            u16* dB = sB[b ^ 1];
            const bool pf = (kt + 1 < nk);
            const size_t ko = (size_t)(kt + 1) * 64;
            bf16x8 bF[4];

            // ph0: kh0, m 0..3. Stage B0,B1(t+1). Drain A2,A3(t).
            PHASE(0, 0, true,
                { if (pf) { GLDS(gB + ko,                      &dB[0 * 4096 + tid * 8]);
                            GLDS(gB + (size_t)1 * 64 * K + ko, &dB[1 * 4096 + tid * 8]); } },
                { if (pf) asm volatile("s_waitcnt vmcnt(2)" ::: "memory");
                  else    asm volatile("s_waitcnt vmcnt(0)" ::: "memory"); })
            // ph1: kh0, m 4..7. Stage B2,B3.
            PHASE(1, 0, false,
                { if (pf) { GLDS(gB + (size_t)2 * 64 * K + ko, &dB[2 * 4096 + tid * 8]);
                            GLDS(gB + (size_t)3 * 64 * K + ko, &dB[3 * 4096 + tid * 8]); } },
                { })
            // ph2: kh1, m 0..3. Stage A0,A1.
            PHASE(0, 1, true,
                { if (pf) { GLDS(gA + ko,                      &dA[0 * 4096 + tid * 8]);
                            GLDS(gA + (size_t)1 * 32 * K + ko, &dA[1 * 4096 + tid * 8]); } },
                { })
            // ph3: kh1, m 4..7. Stage A2,A3. LOAD-BEARING drain of B0-3,A0,A1(t+1)
            // for next ph0's early ds_reads.
            PHASE(1, 1, false,
                { if (pf) { GLDS(gA + (size_t)2 * 32 * K + ko, &dA[2 * 4096 + tid * 8]);
                            GLDS(gA + (size_t)3 * 32 * K + ko, &dA[3 * 4096 + tid * 8]); } },
                { if (pf) asm volatile("s_waitcnt vmcnt(2)" ::: "memory"); })
        }

        const int bmC = bm, bnC = bn;
        a += gridDim.x;
        const bool more = (a < ntiles);
        if (more) {
            wgl = a >> 3; bm = (a & 7) * 8 + (wgl & 7); bn = wgl >> 3;
            gA = A + (size_t)(bm * 256 + rowA) * K + colE;
            gB = W + (size_t)(bn * 256 + rp) * K + colE;
            #pragma unroll
            for (int w = 0; w < 4; ++w) GLDS(gB + (size_t)w * 64 * K, &sB[0][w * 4096 + tid * 8]);
            #pragma unroll
            for (int p = 0; p < 4; ++p) GLDS(gA + (size_t)p * 32 * K, &sA[0][p * 4096 + tid * 8]);
        }

        // fused logits: wave wc owns head bnC*4+wc of the q columns (bnC<4)
        if (awout != nullptr && bnC < 4) {
            const int h = bnC * 4 + wc;
            float qav[4];
            #pragma unroll
            for (int n = 0; n < 4; ++n) qav[n] = qa[bnC * 256 + wc * 64 + n * 16 + li];
            #pragma unroll
            for (int mf = 0; mf < 8; ++mf) {
                #pragma unroll
                for (int r = 0; r < 4; ++r) {
                    float d = acc[mf][0][r] * qav[0] + acc[mf][1][r] * qav[1]
                            + acc[mf][2][r] * qav[2] + acc[mf][3][r] * qav[3];
                    d += __shfl_xor(d, 1);
                    d += __shfl_xor(d, 2);
                    d += __shfl_xor(d, 4);
                    d += __shfl_xor(d, 8);
                    if (li == 0) {
                        int row = bmC * 256 + wr * 128 + mf * 16 + ((lane >> 4) << 2) + r;
                        float ma = (1.0f - mask[row]) * -10000.0f;
                        awout[(((size_t)(row >> 12)) * NH + h) * SEQ + (row & (SEQ - 1))] =
                            expf(d * 0.125f + ma);
                    }
                }
            }
        }

        #pragma unroll
        for (int mf = 0; mf < 8; ++mf) {
            int row0 = bmC * 256 + wr * 128 + mf * 16 + ((lane >> 4) << 2);
            #pragma unroll
            for (int n = 0; n < 4; ++n) {
                int col = bnC * 256 + wc * 64 + n * 16 + li;
                #pragma unroll
                for (int r = 0; r < 4; ++r)
                    C[(size_t)(row0 + r) * ldc + col] = f2bf(acc[mf][n][r]);
            }
        }
        if (!more) break;
    }
}

// ---------------------------------------------------------------- windowed scan attention, 2 heads/block
// fused==0: out_bf <- windowed avg (bf16). fused==1: outF <- res + win*v (write-only).
__global__ __launch_bounds__(512) void attn_win2(
    const u16* __restrict__ x, int xstride,
    const float* __restrict__ aw_g,
    u16* __restrict__ out_bf,
    const u16* __restrict__ resv,   // qkv base: res in cols 0..1023, v in cols 2048..3071
    float* __restrict__ outF,
    int fused)
{
    int c = blockIdx.x, h2 = blockIdx.y, b = blockIdx.z;
    __shared__ float awl[2][2][WIN];     // [head][chunk][j]
    __shared__ float2 sts[2][8][64];     // [chunk][wave][lane]
    __shared__ float stz[2][8][2];       // [chunk][wave][head]

    int t = threadIdx.x, wave = t >> 6, lane = t & 63;
    int hh = lane >> 5;
    int coff = hh * 64 + (lane & 31) * 2;
    bool havePrev = (c > 0);

    const float* aw0 = aw_g + ((size_t)b * NH + h2 * 2) * SEQ;
    for (int i = t; i < 1024; i += 512) {
        int hd = i >> 9, cc = (i >> 8) & 1, j = i & 255;
        float v = 0.f;
        if (cc == 1) v = aw0[hd * SEQ + c * WIN + j];
        else if (havePrev) v = aw0[hd * SEQ + (c - 1) * WIN + j];
        awl[hd][cc][j] = v;
    }
    __syncthreads();

    const u16* xb = x + (size_t)b * SEQ * xstride + h2 * 128 + coff;
    int jp0 = (havePrev ? c - 1 : c) * WIN;   // clamped when c==0 (aw=0 kills it)
    int jc0 = c * WIN;
    int j0 = wave * 32;

    // step A: per-wave sub-strip totals over rows [j0, j0+32) of both chunks
    float s0a = 0, s0b = 0, s1a = 0, s1b = 0, z0 = 0, z1 = 0;
    #pragma unroll 8
    for (int jj = 0; jj < 32; ++jj) {
        int j = j0 + jj;
        float ap = awl[hh][0][j], ac = awl[hh][1][j];
        unsigned up = *(const unsigned*)(xb + (size_t)(jp0 + j) * xstride);
        unsigned uc = *(const unsigned*)(xb + (size_t)(jc0 + j) * xstride);
        s0a += ap * bfu(up & 0xffff); s0b += ap * bfu(up >> 16); z0 += ap;
        s1a += ac * bfu(uc & 0xffff); s1b += ac * bfu(uc >> 16); z1 += ac;
    }
    sts[0][wave][lane] = make_float2(s0a, s0b);
    sts[1][wave][lane] = make_float2(s1a, s1b);
    if ((lane & 31) == 0) { stz[0][wave][hh] = z0; stz[1][wave][hh] = z1; }
    __syncthreads();

    // step B: carries + chunk-(c-1) totals
    float cs0a = 0, cs0b = 0, cs1a = 0, cs1b = 0, cz0 = 0, cz1 = 0;
    float totsa = 0, totsb = 0, totz = 0;
    #pragma unroll
    for (int w2 = 0; w2 < 8; ++w2) {
        float2 sp = sts[0][w2][lane];
        float zp = stz[0][w2][hh];
        totsa += sp.x; totsb += sp.y; totz += zp;
        if (w2 < wave) {
            cs0a += sp.x; cs0b += sp.y; cz0 += zp;
            float2 sc = sts[1][w2][lane];
            cs1a += sc.x; cs1b += sc.y; cz1 += stz[1][w2][hh];
        }
    }

    // step C: rescan with carries, emit
    float rpa = cs0a, rpb = cs0b, rca = cs1a, rcb = cs1b, rzp = cz0, rzc = cz1;
    size_t rowbase = (size_t)b * SEQ + jc0;
    #pragma unroll 4
    for (int jj = 0; jj < 32; ++jj) {
        int j = j0 + jj;
        float ap = awl[hh][0][j], ac = awl[hh][1][j];
        unsigned up = *(const unsigned*)(xb + (size_t)(jp0 + j) * xstride);
        unsigned uc = *(const unsigned*)(xb + (size_t)(jc0 + j) * xstride);
        rpa += ap * bfu(up & 0xffff); rpb += ap * bfu(up >> 16); rzp += ap;
        rca += ac * bfu(uc & 0xffff); rcb += ac * bfu(uc >> 16); rzc += ac;
        float inv = 1.f / (rzc + totz - rzp);
        float wva = (rca + totsa - rpa) * inv;
        float wvb = (rcb + totsb - rpb) * inv;
        if (fused) {
            size_t roff = (rowbase + j) * 3072 + h2 * 128 + coff;
            unsigned rr = *(const unsigned*)(resv + roff);
            unsigned vv = *(const unsigned*)(resv + roff + 2048);
            float2 o;
            o.x = bfu(rr & 0xffff) + wva * bfu(vv & 0xffff);
            o.y = bfu(rr >> 16)    + wvb * bfu(vv >> 16);
            *(float2*)(outF + (rowbase + j) * HID + h2 * 128 + coff) = o;
        } else {
            unsigned pk = (unsigned)f2bf(wva) | ((unsigned)f2bf(wvb) << 16);
            *(unsigned*)(out_bf + (rowbase + j) * HID + h2 * 128 + coff) = pk;
        }
    }
}

// ---------------------------------------------------------------- residual + LN2 + fused key-attn logits
__global__ __launch_bounds__(256) void resid_ln2(
    const u16* h, u16* qkv,
    const float* __restrict__ g, const float* __restrict__ b,
    const float* __restrict__ ka, const float* __restrict__ mask,
    u16* mixed, float* __restrict__ aw2)
{
    int row = blockIdx.x;
    int t = threadIdx.x;
    ushort4 h4 = ((const ushort4*)(h + (size_t)row * HID))[t];
    ushort4 p4 = ((const ushort4*)(qkv + (size_t)row * 3072))[t];
    ushort4 k4 = ((const ushort4*)(qkv + (size_t)row * 3072 + 1024))[t];
    float r0 = bfu(h4.x) + bfu(p4.x) * bfu(k4.x);
    float r1 = bfu(h4.y) + bfu(p4.y) * bfu(k4.y);
    float r2 = bfu(h4.z) + bfu(p4.z) * bfu(k4.z);
    float r3 = bfu(h4.w) + bfu(p4.w) * bfu(k4.w);
    ushort4 rb;
    rb.x = f2bf(r0); rb.y = f2bf(r1); rb.z = f2bf(r2); rb.w = f2bf(r3);
    ((ushort4*)(qkv + (size_t)row * 3072))[t] = rb;   // residual bf16 over dead pq

    float s  = r0 + r1 + r2 + r3;
    float ss = r0 * r0 + r1 * r1 + r2 * r2 + r3 * r3;
    __shared__ float red[8];
    #pragma unroll
    for (int off = 32; off; off >>= 1) { s += __shfl_down(s, off); ss += __shfl_down(ss, off); }
    int wave = t >> 6, lane = t & 63;
    if (lane == 0) { red[wave] = s; red[4 + wave] = ss; }
    __syncthreads();
    float S  = red[0] + red[1] + red[2] + red[3];
    float SS = red[4] + red[5] + red[6] + red[7];
    float mean = S * (1.f / HID);
    float var  = SS * (1.f / HID) - mean * mean;
    float inv  = rsqrtf(var + LN_EPS);
    float4 gv = ((const float4*)g)[t];
    float4 bv = ((const float4*)b)[t];
    float n0 = (r0 - mean) * inv * gv.x + bv.x;
    float n1 = (r1 - mean) * inv * gv.y + bv.y;
    float n2 = (r2 - mean) * inv * gv.z + bv.z;
    float n3 = (r3 - mean) * inv * gv.w + bv.w;
    ushort4 o;
    o.x = f2bf(n0); o.y = f2bf(n1); o.z = f2bf(n2); o.w = f2bf(n3);
    ((ushort4*)(mixed + (size_t)row * HID))[t] = o;

    // fused logits for second attention: head = t>>4
    float4 kv = ((const float4*)ka)[t];
    float partial = n0 * kv.x + n1 * kv.y + n2 * kv.z + n3 * kv.w;
    partial += __shfl_xor(partial, 1);
    partial += __shfl_xor(partial, 2);
    partial += __shfl_xor(partial, 4);
    partial += __shfl_xor(partial, 8);
    if ((t & 15) == 0) {
        int hh = t >> 4;
        int bb = row >> 12, sl = row & (SEQ - 1);
        float ma = (1.0f - mask[row]) * -10000.0f;
        aw2[((size_t)bb * NH + hh) * SEQ + sl] = expf(partial * 0.125f + ma);
    }
}

extern "C" void kernel_launch(void* const* d_in, const int* in_sizes, int n_in,
                              void* d_out, int out_size, void* d_ws, size_t ws_size,
                              hipStream_t stream)
{
    const float* hidden = (const float*)d_in[0];
    const float* mask   = (const float*)d_in[1];
    const float* Wq     = (const float*)d_in[2];
    const float* Wk     = (const float*)d_in[3];
    const float* Wv     = (const float*)d_in[4];
    const float* Wp     = (const float*)d_in[5];
    const float* qa     = (const float*)d_in[6];
    const float* ka     = (const float*)d_in[7];
    const float* g1     = (const float*)d_in[8];
    const float* b1     = (const float*)d_in[9];
    const float* g2     = (const float*)d_in[10];
    const float* b2     = (const float*)d_in[11];
    float* out = (float*)d_out;

    // workspace: 8 + 32 + 96 + 32 + 1 + 1 = 170 MB
    char* ws = (char*)d_ws;
    u16* wbf = (u16*)ws;       ws += (size_t)4 * 1024 * 1024 * 2;     //  8 MB  Wq|Wk|Wv|Wp bf16
    u16* hbf = (u16*)ws;       ws += (size_t)NROWS * HID * 2;         // 32 MB  h (later: mixed, in place)
    u16* qkv = (u16*)ws;       ws += (size_t)NROWS * 3072 * 2;        // 96 MB  q|k|v (q-cols: pq, then residual)
    u16* pooled = (u16*)ws;    ws += (size_t)NROWS * HID * 2;         // 32 MB  pooled_q
    float* aw1 = (float*)ws;   ws += (size_t)BATCH * NH * SEQ * 4;    //  1 MB
    float* aw2 = (float*)ws;                                          //  1 MB

    ln1_conv<<<NROWS + 4096, 256, 0, stream>>>(hidden, g1, b1, hbf, Wq, Wk, Wv, Wp, wbf);
    // qkv GEMM (fused attn1 logits): 64 bm x 12 bn = 768 tiles, persistent 256 blocks
    gemm256<<<256, 512, 0, stream>>>(hbf, wbf, qkv, HID, 3072, 768, qa, mask, aw1);
    attn_win2<<<dim3(SEQ / WIN, NH / 2, BATCH), 512, 0, stream>>>(
        qkv, 3072, aw1, pooled, (const u16*)nullptr, (float*)nullptr, 0);
    // pooled_q @ Wp.T -> qkv cols 0..1023 (q is dead): 64 bm x 4 bn = 256 tiles
    gemm256<<<256, 512, 0, stream>>>(pooled, wbf + (size_t)3 * 1024 * 1024, qkv, HID, 3072, 256,
                                     (const float*)nullptr, (const float*)nullptr, (float*)nullptr);
    resid_ln2<<<NROWS, 256, 0, stream>>>(hbf, qkv, g2, b2, ka, mask, hbf, aw2);
    // second attention fused with final: out = res + win * v
    attn_win2<<<dim3(SEQ / WIN, NH / 2, BATCH), 512, 0, stream>>>(
        hbf, HID, aw2, (u16*)nullptr, qkv, out, 1);
}